// Round 12
// baseline (1430.999 us; speedup 1.0000x reference)
//
#include <hip/hip_runtime.h>
#include <hip/hip_bf16.h>

#define TT 4096
#define FF 80
#define HH 64
#define NB 128
#define TB 256    // proj: timesteps per block
#define CT 8      // proj: timesteps per staging phase
#define XPAD 104  // proj LDS row stride in bf16 elems
#define LOG2E 1.44269504088896340736f

using short8  = __attribute__((ext_vector_type(8))) short;   // 8 bf16 = 4 VGPR
using floatx4 = __attribute__((ext_vector_type(4))) float;

__device__ __forceinline__ float sigm(float x)  { return __builtin_amdgcn_rcpf(1.0f + __expf(-x)); }
__device__ __forceinline__ float tanh_f(float x){ return 1.0f - 2.0f * __builtin_amdgcn_rcpf(1.0f + __expf(2.0f * x)); }

__device__ __forceinline__ unsigned short f2bf(float f) {    // RNE f32->bf16
    unsigned u = __builtin_bit_cast(unsigned, f);
    u += 0x7fffu + ((u >> 16) & 1u);
    return (unsigned short)(u >> 16);
}
__device__ __forceinline__ float bflo(unsigned u) { return __builtin_bit_cast(float, u << 16); }
__device__ __forceinline__ float bfhi(unsigned u) { return __builtin_bit_cast(float, u & 0xffff0000u); }
__device__ __forceinline__ unsigned packbf2(float a, float b) {
    return (unsigned)f2bf(a) | ((unsigned)f2bf(b) << 16);
}

// single-instruction f32->bf16 (RNE) for the critical path
__device__ __forceinline__ unsigned short cvt_bf16(float f) {
    unsigned r;
    asm("v_cvt_pk_bf16_f32 %0, %1, %2" : "=v"(r) : "v"(f), "v"(f));
    return (unsigned short)r;
}

// LDS-visibility-only barrier: global loads stay in flight across it.
__device__ __forceinline__ void bar_lgkm() {
    asm volatile("s_waitcnt lgkmcnt(0)" ::: "memory");
    __builtin_amdgcn_s_barrier();
}

__device__ __forceinline__ floatx4 mfma16(short8 a, short8 b, floatx4 c) {
    return __builtin_amdgcn_mfma_f32_16x16x32_bf16(a, b, c, 0, 0, 0);
}

// activations on log2e-PRE-SCALED inputs (s = x * log2e):
//   sigmoid(x) = rcp(1 + 2^(-s))
//   tanh(x)    = 1 - 2*rcp(1 + 2^(2s))
__device__ __forceinline__ float sigm_s(float s) {
    return __builtin_amdgcn_rcpf(1.0f + __builtin_amdgcn_exp2f(-s));
}
__device__ __forceinline__ float tanh_s(float s) {
    return fmaf(-2.0f, __builtin_amdgcn_rcpf(1.0f + __builtin_amdgcn_exp2f(s + s)), 1.0f);
}

// ---------------------------------------------------------------------------
// PROJ (MFMA): PRE[chain][t][unit*4 + gatetype] bf16, PRE-SCALED by log2e
// (w_ih and biases scaled at load; scan's W_hh likewise -> gates come out of
// the MFMA already in the 2^x domain).
// ---------------------------------------------------------------------------
__global__ __launch_bounds__(256, 1)
void lstm_proj_mfma(const float* __restrict__ x,
                    const float* __restrict__ w_ih_f, const float* __restrict__ b_ih_f,
                    const float* __restrict__ b_hh_f,
                    const float* __restrict__ w_ih_b, const float* __restrict__ b_ih_b,
                    const float* __restrict__ b_hh_b,
                    unsigned short* __restrict__ pre)
{
    const int blk   = blockIdx.x;
    const int ttile = blk & 15;
    const int dgrp  = blk >> 4;
    const int dir   = dgrp >> 3;
    const int bgrp  = dgrp & 7;
    const int tid   = threadIdx.x;
    const int wv    = tid >> 6;
    const int l     = tid & 63;
    const int b16   = l & 15;
    const int g     = l >> 4;
    const int t0    = ttile * TB;

    const float* __restrict__ wih = dir ? w_ih_b : w_ih_f;
    const float* __restrict__ bi  = dir ? b_ih_b : b_ih_f;
    const float* __restrict__ bh  = dir ? b_hh_b : b_hh_f;

    short8 Bf[4][3];
    float  bias[4];
    #pragma unroll
    for (int tp = 0; tp < 4; ++tp) {
        const int n = 64 * wv + 16 * tp + b16;
        bias[tp] = (bi[n] + bh[n]) * LOG2E;
        #pragma unroll
        for (int kap = 0; kap < 3; ++kap) {
            const int f0 = 32 * kap + 8 * g;
            float f[8];
            if (f0 < FF) {
                const float4 v0 = *reinterpret_cast<const float4*>(wih + n * FF + f0);
                const float4 v1 = *reinterpret_cast<const float4*>(wih + n * FF + f0 + 4);
                f[0]=v0.x; f[1]=v0.y; f[2]=v0.z; f[3]=v0.w;
                f[4]=v1.x; f[5]=v1.y; f[6]=v1.z; f[7]=v1.w;
            } else {
                #pragma unroll
                for (int j = 0; j < 8; ++j) f[j] = 0.0f;
            }
            short8 s;
            #pragma unroll
            for (int j = 0; j < 8; ++j) s[j] = (short)f2bf(f[j] * LOG2E);
            Bf[tp][kap] = s;
        }
    }

    __shared__ __align__(16) unsigned short xa[2][CT][16][XPAD];
    for (int i = tid; i < 2 * CT * 16 * XPAD / 2; i += 256)
        reinterpret_cast<unsigned*>(&xa[0][0][0][0])[i] = 0u;
    __syncthreads();

    const int nph = TB / CT;   // 32

    {   // prologue
        const int t0p = t0;
        const int te_base = dir ? (TT - CT - t0p) : t0p;
        float2 st[20];
        #pragma unroll
        for (int q = 0; q < 20; ++q) {
            const int i = q * 256 + tid;
            const int b = i / 320, r2 = i % 320;
            const int te_rel = r2 / 40, fq = r2 % 40;
            st[q] = *reinterpret_cast<const float2*>(
                x + ((size_t)(bgrp * 16 + b) * TT + te_base + te_rel) * FF + 2 * fq);
        }
        #pragma unroll
        for (int q = 0; q < 20; ++q) {
            const int i = q * 256 + tid;
            const int b = i / 320, r2 = i % 320;
            const int te_rel = r2 / 40, fq = r2 % 40;
            const int t_off = dir ? (CT - 1 - te_rel) : te_rel;
            *reinterpret_cast<unsigned*>(&xa[0][t_off][b][2 * fq]) = packbf2(st[q].x, st[q].y);
        }
    }
    __syncthreads();

    #pragma unroll 1
    for (int ph = 0; ph < nph; ++ph) {
        const int cur = ph & 1;
        const bool have = (ph + 1) < nph;

        float2 st[20];
        if (have) {
            const int t0p = t0 + (ph + 1) * CT;
            const int te_base = dir ? (TT - CT - t0p) : t0p;
            #pragma unroll
            for (int q = 0; q < 20; ++q) {
                const int i = q * 256 + tid;
                const int b = i / 320, r2 = i % 320;
                const int te_rel = r2 / 40, fq = r2 % 40;
                st[q] = *reinterpret_cast<const float2*>(
                    x + ((size_t)(bgrp * 16 + b) * TT + te_base + te_rel) * FF + 2 * fq);
            }
        }

        #pragma unroll
        for (int t_off = 0; t_off < CT; ++t_off) {
            short8 A[3];
            #pragma unroll
            for (int kap = 0; kap < 3; ++kap)
                A[kap] = *reinterpret_cast<const short8*>(&xa[cur][t_off][b16][32 * kap + 8 * g]);
            const int t = t0 + ph * CT + t_off;
            #pragma unroll
            for (int tp = 0; tp < 4; ++tp) {
                floatx4 acc = {bias[tp], bias[tp], bias[tp], bias[tp]};
                acc = mfma16(A[0], Bf[tp][0], acc);
                acc = mfma16(A[1], Bf[tp][1], acc);
                acc = mfma16(A[2], Bf[tp][2], acc);
                const int p = (16 * tp + b16) * 4 + wv;   // unit*4 + gatetype
                #pragma unroll
                for (int r = 0; r < 4; ++r) {
                    const int bb = dir * NB + bgrp * 16 + 4 * g + r;
                    pre[((size_t)bb * TT + t) * 256 + p] = f2bf(acc[r]);
                }
            }
        }

        if (have) {
            #pragma unroll
            for (int q = 0; q < 20; ++q) {
                const int i = q * 256 + tid;
                const int b = i / 320, r2 = i % 320;
                const int te_rel = r2 / 40, fq = r2 % 40;
                const int t_off = dir ? (CT - 1 - te_rel) : te_rel;
                *reinterpret_cast<unsigned*>(&xa[cur ^ 1][t_off][b][2 * fq]) = packbf2(st[q].x, st[q].y);
            }
        }
        bar_lgkm();
    }
}

// ---------------------------------------------------------------------------
// SCAN v7 = round-9 scan (measured best, 1178 us) + critical-path cuts only:
//  1. MFMA pair UN-CHAINED: two independent MFMAs + scalar add of [0]
//     (removes one MFMA latency from the serial path; same f32 sum).
//  2. log2e-prescaled gates -> activations use raw v_exp_f32, no mul.
//  3. v_cvt_pk_bf16_f32 for the h store (1 instr vs 4 serial bit-ops).
// Layout, ring, zero-region addressing identical to round 9 (r11 showed the
// bank conflicts are off the critical path; the cndmask fix cost more).
// ---------------------------------------------------------------------------
__global__ __launch_bounds__(256, 1)
void lstm_scan_mfma4(const unsigned short* __restrict__ pre,  // [256][TT][256]
                     const float* __restrict__ w_hh_f, const float* __restrict__ w_hh_b,
                     float* __restrict__ h_out)               // [256][64]
{
    const int chain = blockIdx.x;       // dir*128 + bat
    const int dir   = chain >> 7;
    const int tid   = threadIdx.x;
    const int wv    = tid >> 6;         // unit window: 16*wv .. 16*wv+15
    const int l     = tid & 63;
    const int b16   = l & 15;           // A row / C col
    const int g4    = l >> 4;           // k-group
    const bool actC = (g4 == 0);        // C row-0 lanes (l = 0..15): cell owners
    const int  u    = 16 * wv + b16;    // this lane's unit (valid when actC)

    const float* __restrict__ whh = dir ? w_hh_b : w_hh_f;

    // B-fragments (scaled by log2e): gate gt (0:i 1:f 2:g 3:o), kap (K chunk).
    short8 Bf[4][2];
    #pragma unroll
    for (int gt = 0; gt < 4; ++gt) {
        const int n = gt * 64 + 16 * wv + b16;
        #pragma unroll
        for (int kap = 0; kap < 2; ++kap) {
            const float4 v0 = *reinterpret_cast<const float4*>(whh + n * HH + 32 * kap + 8 * g4);
            const float4 v1 = *reinterpret_cast<const float4*>(whh + n * HH + 32 * kap + 8 * g4 + 4);
            short8 s;
            s[0]=(short)f2bf(v0.x*LOG2E); s[1]=(short)f2bf(v0.y*LOG2E);
            s[2]=(short)f2bf(v0.z*LOG2E); s[3]=(short)f2bf(v0.w*LOG2E);
            s[4]=(short)f2bf(v1.x*LOG2E); s[5]=(short)f2bf(v1.y*LOG2E);
            s[6]=(short)f2bf(v1.z*LOG2E); s[7]=(short)f2bf(v1.w*LOG2E);
            Bf[gt][kap] = s;
        }
    }

    // LDS: bytes [0,128) = h buf0 (bf16[64]), [128,256) = h buf1,
    //      [256,384) = permanently-zero region (A rows 1-15 read here).
    __shared__ __align__(16) unsigned short hls[192];
    if (tid < 96) reinterpret_cast<unsigned*>(hls)[tid] = 0u;

    // PRE ring: actC lanes read uint2 = {i,f | g,o} bf16 at [chain][t][u*4].
    const uint2* __restrict__ prow = reinterpret_cast<const uint2*>(
        pre + (size_t)chain * TT * 256 + u * 4);
    uint2 prr[4];
    if (actC) {
        #pragma unroll
        for (int d = 0; d < 4; ++d) prr[d] = prow[(size_t)d * 64];   // t stride = 64 uint2
    }

    float c = 0.0f, h = 0.0f;
    __syncthreads();

    const char* lb = reinterpret_cast<const char*>(hls);
    char* lw = reinterpret_cast<char*>(hls);

    #pragma unroll 1
    for (int t = 0; t < TT; t += 4) {
        #pragma unroll
        for (int d = 0; d < 4; ++d) {
            const int cur = d & 1;       // (t+d)&1 since t%4==0

            // A fragments: row-0 lanes read h(t); others read zeros (r9 layout).
            const int abase = (b16 == 0 ? 128 * cur : 256) + 16 * g4;
            const short8 A0 = *reinterpret_cast<const short8*>(lb + abase);
            const short8 A1 = *reinterpret_cast<const short8*>(lb + abase + 64);

            // capture PRE for this step, then reload ring slot for t+d+4
            uint2 pc = prr[d];
            if (actC) prr[d] = prow[(size_t)((t + d + 4) & (TT - 1)) * 64];

            // two INDEPENDENT MFMAs per gate (overlapped latency) + scalar add
            const floatx4 z = {0.f, 0.f, 0.f, 0.f};
            floatx4 ci0 = mfma16(A0, Bf[0][0], z), ci1 = mfma16(A1, Bf[0][1], z);
            floatx4 cf0 = mfma16(A0, Bf[1][0], z), cf1 = mfma16(A1, Bf[1][1], z);
            floatx4 cg0 = mfma16(A0, Bf[2][0], z), cg1 = mfma16(A1, Bf[2][1], z);
            floatx4 co0 = mfma16(A0, Bf[3][0], z), co1 = mfma16(A1, Bf[3][1], z);

            if (actC) {
                const float gi = bflo(pc.x) + (ci0[0] + ci1[0]);   // scaled by log2e
                const float gf = bfhi(pc.x) + (cf0[0] + cf1[0]);
                const float gg = bflo(pc.y) + (cg0[0] + cg1[0]);
                const float go = bfhi(pc.y) + (co0[0] + co1[0]);
                c = fmaf(sigm_s(gf), c, sigm_s(gi) * tanh_s(gg));
                h = sigm_s(go) * tanh_s(c * LOG2E);
                *reinterpret_cast<unsigned short*>(lw + 128 * (cur ^ 1) + 2 * u) = cvt_bf16(h);
            }
            bar_lgkm();                  // LDS visibility only; ring stays in flight
        }
    }

    if (actC) h_out[(size_t)chain * HH + u] = h;
}

// ---------------------------------------------------------------------------
// Fallback: fully fused scan (round-1 kernel) if ws is too small for PRE.
// ---------------------------------------------------------------------------
__global__ __launch_bounds__(256, 1)
void lstm_scan_fused_kernel(const float* __restrict__ x,
                            const float* __restrict__ w_ih_f, const float* __restrict__ w_hh_f,
                            const float* __restrict__ b_ih_f, const float* __restrict__ b_hh_f,
                            const float* __restrict__ w_ih_b, const float* __restrict__ w_hh_b,
                            const float* __restrict__ b_ih_b, const float* __restrict__ b_hh_b,
                            float* __restrict__ h_out)
{
    const int blk = blockIdx.x;
    const int dir = blk >> 7;
    const int bat = blk & 127;
    const int tid = threadIdx.x;
    const int wv  = tid >> 6;
    const int ln  = tid & 63;

    const float* __restrict__ w_ih = dir ? w_ih_b : w_ih_f;
    const float* __restrict__ w_hh = dir ? w_hh_b : w_hh_f;
    const float* __restrict__ b_ih = dir ? b_ih_b : b_ih_f;
    const float* __restrict__ b_hh = dir ? b_hh_b : b_hh_f;

    float wi[FF], wh[HH];
    #pragma unroll
    for (int f = 0; f < FF; ++f) wi[f] = w_ih[tid * FF + f];
    #pragma unroll
    for (int j = 0; j < HH; ++j) wh[j] = w_hh[tid * HH + j];
    const float bias = b_ih[tid] + b_hh[tid];

    __shared__ float xs[2][FF];
    __shared__ float hbuf[4][HH];
    __shared__ float gbuf[2][256];

    const float* __restrict__ xrow = x + (size_t)bat * (TT * FF);
    float c = 0.0f, hreg = 0.0f;
    hbuf[wv][ln] = 0.0f;

    float xA = 0.0f;
    if (tid < FF) {
        xs[0][tid] = xrow[(size_t)(dir ? (TT - 1) : 0) * FF + tid];
        xA         = xrow[(size_t)(dir ? (TT - 2) : 1) * FF + tid];
    }
    __syncthreads();

    #pragma unroll 1
    for (int t = 0; t < TT; ++t) {
        const int cur = t & 1, nxt = cur ^ 1;
        float a0 = 0.f, a1 = 0.f, a2 = 0.f, a3 = 0.f;
        const float4* xs4 = reinterpret_cast<const float4*>(xs[cur]);
        #pragma unroll
        for (int f = 0; f < FF / 4; ++f) {
            float4 v = xs4[f];
            a0 = fmaf(wi[4*f+0], v.x, a0);
            a1 = fmaf(wi[4*f+1], v.y, a1);
            a2 = fmaf(wi[4*f+2], v.z, a2);
            a3 = fmaf(wi[4*f+3], v.w, a3);
        }
        const float4* hb4 = reinterpret_cast<const float4*>(hbuf[wv]);
        #pragma unroll
        for (int j = 0; j < HH / 4; ++j) {
            float4 v = hb4[j];
            a0 = fmaf(wh[4*j+0], v.x, a0);
            a1 = fmaf(wh[4*j+1], v.y, a1);
            a2 = fmaf(wh[4*j+2], v.z, a2);
            a3 = fmaf(wh[4*j+3], v.w, a3);
        }
        gbuf[cur][tid] = ((a0 + a1) + (a2 + a3)) + bias;

        if (tid < FF) {
            if (t + 1 < TT) xs[nxt][tid] = xA;
            if (t + 2 < TT) xA = xrow[(size_t)(dir ? (TT - 3 - t) : (t + 2)) * FF + tid];
        }
        __syncthreads();

        const float gi = gbuf[cur][ln];
        const float gf = gbuf[cur][64 + ln];
        const float gg = gbuf[cur][128 + ln];
        const float go = gbuf[cur][192 + ln];
        c    = sigm(gf) * c + sigm(gi) * tanh_f(gg);
        hreg = sigm(go) * tanh_f(c);
        hbuf[wv][ln] = hreg;
    }

    if (tid < HH) h_out[(size_t)(dir * 128 + bat) * HH + tid] = hreg;
}

__global__ __launch_bounds__(64, 1)
void fc_kernel(const float* __restrict__ h_out,   // [2][NB][HH]
               const float* __restrict__ w_fc,    // [8][128]
               const float* __restrict__ b_fc,    // [8]
               float* __restrict__ out)           // [NB][8]
{
    const int b = blockIdx.x;
    const int o = threadIdx.x;
    if (o < 8) {
        float acc = b_fc[o];
        #pragma unroll 4
        for (int j = 0; j < HH; ++j)
            acc = fmaf(h_out[(size_t)b * HH + j], w_fc[o * 128 + j], acc);
        #pragma unroll 4
        for (int j = 0; j < HH; ++j)
            acc = fmaf(h_out[(size_t)(NB + b) * HH + j], w_fc[o * 128 + 64 + j], acc);
        out[b * 8 + o] = acc;
    }
}

extern "C" void kernel_launch(void* const* d_in, const int* in_sizes, int n_in,
                              void* d_out, int out_size, void* d_ws, size_t ws_size,
                              hipStream_t stream) {
    const float* x      = (const float*)d_in[0];
    const float* w_ih_f = (const float*)d_in[2];
    const float* w_hh_f = (const float*)d_in[3];
    const float* b_ih_f = (const float*)d_in[4];
    const float* b_hh_f = (const float*)d_in[5];
    const float* w_ih_b = (const float*)d_in[6];
    const float* w_hh_b = (const float*)d_in[7];
    const float* b_ih_b = (const float*)d_in[8];
    const float* b_hh_b = (const float*)d_in[9];
    const float* w_fc   = (const float*)d_in[10];
    const float* b_fc   = (const float*)d_in[11];
    float* out = (float*)d_out;

    const size_t pre_bytes = (size_t)2 * NB * TT * 256 * 2;   // 512 MiB bf16
    const size_t need      = pre_bytes + 64 * 1024;

    if (ws_size >= need) {
        unsigned short* pre = (unsigned short*)d_ws;
        float* h_out = (float*)((char*)d_ws + pre_bytes);
        lstm_proj_mfma<<<dim3(256), dim3(256), 0, stream>>>(
            x, w_ih_f, b_ih_f, b_hh_f, w_ih_b, b_ih_b, b_hh_b, pre);
        lstm_scan_mfma4<<<dim3(256), dim3(256), 0, stream>>>(
            pre, w_hh_f, w_hh_b, h_out);
        fc_kernel<<<dim3(128), dim3(64), 0, stream>>>(h_out, w_fc, b_fc, out);
    } else {
        float* h_out = (float*)d_ws;   // 64 KiB
        lstm_scan_fused_kernel<<<dim3(256), dim3(256), 0, stream>>>(
            x, w_ih_f, w_hh_f, b_ih_f, b_hh_f,
            w_ih_b, w_hh_b, b_ih_b, b_hh_b, h_out);
        fc_kernel<<<dim3(128), dim3(64), 0, stream>>>(h_out, w_fc, b_fc, out);
    }
}

// Round 13
// 1333.739 us; speedup vs baseline: 1.0729x; 1.0729x over previous
//
#include <hip/hip_runtime.h>
#include <hip/hip_bf16.h>

#define TT 4096
#define FF 80
#define HH 64
#define NB 128
#define TB 256    // proj: timesteps per block
#define CT 8      // proj: timesteps per staging phase
#define XPAD 104  // proj LDS row stride in bf16 elems
#define LOG2E 1.44269504088896340736f

using short8  = __attribute__((ext_vector_type(8))) short;   // 8 bf16 = 4 VGPR
using floatx4 = __attribute__((ext_vector_type(4))) float;

__device__ __forceinline__ float sigm(float x)  { return __builtin_amdgcn_rcpf(1.0f + __expf(-x)); }
__device__ __forceinline__ float tanh_f(float x){ return 1.0f - 2.0f * __builtin_amdgcn_rcpf(1.0f + __expf(2.0f * x)); }

__device__ __forceinline__ unsigned short f2bf(float f) {    // RNE f32->bf16
    unsigned u = __builtin_bit_cast(unsigned, f);
    u += 0x7fffu + ((u >> 16) & 1u);
    return (unsigned short)(u >> 16);
}
__device__ __forceinline__ float bflo(unsigned u) { return __builtin_bit_cast(float, u << 16); }
__device__ __forceinline__ float bfhi(unsigned u) { return __builtin_bit_cast(float, u & 0xffff0000u); }
__device__ __forceinline__ unsigned packbf2(float a, float b) {
    return (unsigned)f2bf(a) | ((unsigned)f2bf(b) << 16);
}

// single-instruction f32->bf16 (RNE) for the critical path
__device__ __forceinline__ unsigned short cvt_bf16(float f) {
    unsigned r;
    asm("v_cvt_pk_bf16_f32 %0, %1, %2" : "=v"(r) : "v"(f), "v"(f));
    return (unsigned short)r;
}

// LDS-visibility-only barrier: global loads stay in flight across it.
__device__ __forceinline__ void bar_lgkm() {
    asm volatile("s_waitcnt lgkmcnt(0)" ::: "memory");
    __builtin_amdgcn_s_barrier();
}

__device__ __forceinline__ floatx4 mfma16(short8 a, short8 b, floatx4 c) {
    return __builtin_amdgcn_mfma_f32_16x16x32_bf16(a, b, c, 0, 0, 0);
}

// activations on log2e-PRE-SCALED inputs (s = x * log2e):
//   sigmoid(x) = rcp(1 + 2^(-s)) ; tanh(x) = 1 - 2*rcp(1 + 2^(2s))
__device__ __forceinline__ float sigm_s(float s) {
    return __builtin_amdgcn_rcpf(1.0f + __builtin_amdgcn_exp2f(-s));
}
__device__ __forceinline__ float tanh_s(float s) {
    return fmaf(-2.0f, __builtin_amdgcn_rcpf(1.0f + __builtin_amdgcn_exp2f(s + s)), 1.0f);
}

// ---------------------------------------------------------------------------
// PROJ (MFMA): PRE[chain][t][unit*4 + gatetype] bf16, PRE-SCALED by log2e.
// Structure identical to rounds 9-12 (passed every round).
// ---------------------------------------------------------------------------
__global__ __launch_bounds__(256, 1)
void lstm_proj_mfma(const float* __restrict__ x,
                    const float* __restrict__ w_ih_f, const float* __restrict__ b_ih_f,
                    const float* __restrict__ b_hh_f,
                    const float* __restrict__ w_ih_b, const float* __restrict__ b_ih_b,
                    const float* __restrict__ b_hh_b,
                    unsigned short* __restrict__ pre)
{
    const int blk   = blockIdx.x;
    const int ttile = blk & 15;
    const int dgrp  = blk >> 4;
    const int dir   = dgrp >> 3;
    const int bgrp  = dgrp & 7;
    const int tid   = threadIdx.x;
    const int wv    = tid >> 6;
    const int l     = tid & 63;
    const int b16   = l & 15;
    const int g     = l >> 4;
    const int t0    = ttile * TB;

    const float* __restrict__ wih = dir ? w_ih_b : w_ih_f;
    const float* __restrict__ bi  = dir ? b_ih_b : b_ih_f;
    const float* __restrict__ bh  = dir ? b_hh_b : b_hh_f;

    short8 Bf[4][3];
    float  bias[4];
    #pragma unroll
    for (int tp = 0; tp < 4; ++tp) {
        const int n = 64 * wv + 16 * tp + b16;
        bias[tp] = (bi[n] + bh[n]) * LOG2E;
        #pragma unroll
        for (int kap = 0; kap < 3; ++kap) {
            const int f0 = 32 * kap + 8 * g;
            float f[8];
            if (f0 < FF) {
                const float4 v0 = *reinterpret_cast<const float4*>(wih + n * FF + f0);
                const float4 v1 = *reinterpret_cast<const float4*>(wih + n * FF + f0 + 4);
                f[0]=v0.x; f[1]=v0.y; f[2]=v0.z; f[3]=v0.w;
                f[4]=v1.x; f[5]=v1.y; f[6]=v1.z; f[7]=v1.w;
            } else {
                #pragma unroll
                for (int j = 0; j < 8; ++j) f[j] = 0.0f;
            }
            short8 s;
            #pragma unroll
            for (int j = 0; j < 8; ++j) s[j] = (short)f2bf(f[j] * LOG2E);
            Bf[tp][kap] = s;
        }
    }

    __shared__ __align__(16) unsigned short xa[2][CT][16][XPAD];
    for (int i = tid; i < 2 * CT * 16 * XPAD / 2; i += 256)
        reinterpret_cast<unsigned*>(&xa[0][0][0][0])[i] = 0u;
    __syncthreads();

    const int nph = TB / CT;   // 32

    {   // prologue
        const int t0p = t0;
        const int te_base = dir ? (TT - CT - t0p) : t0p;
        float2 st[20];
        #pragma unroll
        for (int q = 0; q < 20; ++q) {
            const int i = q * 256 + tid;
            const int b = i / 320, r2 = i % 320;
            const int te_rel = r2 / 40, fq = r2 % 40;
            st[q] = *reinterpret_cast<const float2*>(
                x + ((size_t)(bgrp * 16 + b) * TT + te_base + te_rel) * FF + 2 * fq);
        }
        #pragma unroll
        for (int q = 0; q < 20; ++q) {
            const int i = q * 256 + tid;
            const int b = i / 320, r2 = i % 320;
            const int te_rel = r2 / 40, fq = r2 % 40;
            const int t_off = dir ? (CT - 1 - te_rel) : te_rel;
            *reinterpret_cast<unsigned*>(&xa[0][t_off][b][2 * fq]) = packbf2(st[q].x, st[q].y);
        }
    }
    __syncthreads();

    #pragma unroll 1
    for (int ph = 0; ph < nph; ++ph) {
        const int cur = ph & 1;
        const bool have = (ph + 1) < nph;

        float2 st[20];
        if (have) {
            const int t0p = t0 + (ph + 1) * CT;
            const int te_base = dir ? (TT - CT - t0p) : t0p;
            #pragma unroll
            for (int q = 0; q < 20; ++q) {
                const int i = q * 256 + tid;
                const int b = i / 320, r2 = i % 320;
                const int te_rel = r2 / 40, fq = r2 % 40;
                st[q] = *reinterpret_cast<const float2*>(
                    x + ((size_t)(bgrp * 16 + b) * TT + te_base + te_rel) * FF + 2 * fq);
            }
        }

        #pragma unroll
        for (int t_off = 0; t_off < CT; ++t_off) {
            short8 A[3];
            #pragma unroll
            for (int kap = 0; kap < 3; ++kap)
                A[kap] = *reinterpret_cast<const short8*>(&xa[cur][t_off][b16][32 * kap + 8 * g]);
            const int t = t0 + ph * CT + t_off;
            #pragma unroll
            for (int tp = 0; tp < 4; ++tp) {
                floatx4 acc = {bias[tp], bias[tp], bias[tp], bias[tp]};
                acc = mfma16(A[0], Bf[tp][0], acc);
                acc = mfma16(A[1], Bf[tp][1], acc);
                acc = mfma16(A[2], Bf[tp][2], acc);
                const int p = (16 * tp + b16) * 4 + wv;   // unit*4 + gatetype
                #pragma unroll
                for (int r = 0; r < 4; ++r) {
                    const int bb = dir * NB + bgrp * 16 + 4 * g + r;
                    pre[((size_t)bb * TT + t) * 256 + p] = f2bf(acc[r]);
                }
            }
        }

        if (have) {
            #pragma unroll
            for (int q = 0; q < 20; ++q) {
                const int i = q * 256 + tid;
                const int b = i / 320, r2 = i % 320;
                const int te_rel = r2 / 40, fq = r2 % 40;
                const int t_off = dir ? (CT - 1 - te_rel) : te_rel;
                *reinterpret_cast<unsigned*>(&xa[cur ^ 1][t_off][b][2 * fq]) = packbf2(st[q].x, st[q].y);
            }
        }
        bar_lgkm();
    }
}

// ---------------------------------------------------------------------------
// SCAN v8 = round-9 scan (measured best, 1178 us) with ONLY:
//  1. log2e-prescaled gates -> activations use raw v_exp (sigm_s/tanh_s).
//  2. v_cvt_pk_bf16_f32 for the h store.
//  3. pointer-bump PRE ring (no per-step address recompute; off-path).
// CHAINED MFMA pair kept (r12 showed un-chaining costs +45cy/step).
// Zero-region A addressing kept (r11 showed conflicts are off-path).
// ---------------------------------------------------------------------------
__global__ __launch_bounds__(256, 1)
void lstm_scan_mfma5(const unsigned short* __restrict__ pre,  // [256][TT][256]
                     const float* __restrict__ w_hh_f, const float* __restrict__ w_hh_b,
                     float* __restrict__ h_out)               // [256][64]
{
    const int chain = blockIdx.x;       // dir*128 + bat
    const int dir   = chain >> 7;
    const int tid   = threadIdx.x;
    const int wv    = tid >> 6;         // unit window: 16*wv .. 16*wv+15
    const int l     = tid & 63;
    const int b16   = l & 15;           // A row / C col
    const int g4    = l >> 4;           // k-group
    const bool actC = (g4 == 0);        // C row-0 lanes (l = 0..15): cell owners
    const int  u    = 16 * wv + b16;    // this lane's unit (valid when actC)

    const float* __restrict__ whh = dir ? w_hh_b : w_hh_f;

    // B-fragments (scaled by log2e): gate gt (0:i 1:f 2:g 3:o), kap (K chunk).
    short8 Bf[4][2];
    #pragma unroll
    for (int gt = 0; gt < 4; ++gt) {
        const int n = gt * 64 + 16 * wv + b16;
        #pragma unroll
        for (int kap = 0; kap < 2; ++kap) {
            const float4 v0 = *reinterpret_cast<const float4*>(whh + n * HH + 32 * kap + 8 * g4);
            const float4 v1 = *reinterpret_cast<const float4*>(whh + n * HH + 32 * kap + 8 * g4 + 4);
            short8 s;
            s[0]=(short)f2bf(v0.x*LOG2E); s[1]=(short)f2bf(v0.y*LOG2E);
            s[2]=(short)f2bf(v0.z*LOG2E); s[3]=(short)f2bf(v0.w*LOG2E);
            s[4]=(short)f2bf(v1.x*LOG2E); s[5]=(short)f2bf(v1.y*LOG2E);
            s[6]=(short)f2bf(v1.z*LOG2E); s[7]=(short)f2bf(v1.w*LOG2E);
            Bf[gt][kap] = s;
        }
    }

    // LDS: bytes [0,128) = h buf0 (bf16[64]), [128,256) = h buf1,
    //      [256,384) = permanently-zero region (A rows 1-15 read here).
    __shared__ __align__(16) unsigned short hls[192];
    if (tid < 96) reinterpret_cast<unsigned*>(hls)[tid] = 0u;

    // PRE ring: actC lanes read uint2 = {i,f | g,o} bf16 at [chain][t][u*4].
    // 4 pre-offset pointers, each bumped +4*512B per ring cycle (no recompute).
    const uint2* __restrict__ prow = reinterpret_cast<const uint2*>(
        pre + (size_t)chain * TT * 256 + u * 4);
    uint2 prr[4] = {{0,0},{0,0},{0,0},{0,0}};
    const uint2* pp0 = prow + 4 * 64;
    const uint2* pp1 = prow + 5 * 64;
    const uint2* pp2 = prow + 6 * 64;
    const uint2* pp3 = prow + 7 * 64;
    if (actC) {
        prr[0] = prow[0 * 64];
        prr[1] = prow[1 * 64];
        prr[2] = prow[2 * 64];
        prr[3] = prow[3 * 64];
    }

    float c = 0.0f, h = 0.0f;
    __syncthreads();

    const char* lb = reinterpret_cast<const char*>(hls);
    char* lw = reinterpret_cast<char*>(hls);

    #pragma unroll 1
    for (int t = 0; t < TT; t += 4) {
        #pragma unroll
        for (int d = 0; d < 4; ++d) {
            const int cur = d & 1;       // (t+d)&1 since t%4==0

            // A fragments: row-0 lanes read h(t); others read zeros (r9 layout).
            const int abase = (b16 == 0 ? 128 * cur : 256) + 16 * g4;
            const short8 A0 = *reinterpret_cast<const short8*>(lb + abase);
            const short8 A1 = *reinterpret_cast<const short8*>(lb + abase + 64);

            // capture PRE for this step, then reload ring slot (pointer bump).
            // Last-4-steps reloads run past the chain into pre/h_out slack:
            // deterministic, mapped, values never consumed.
            uint2 pc = prr[d];
            if (actC) {
                if (d == 0)      { prr[0] = *pp0; pp0 += 256; }
                else if (d == 1) { prr[1] = *pp1; pp1 += 256; }
                else if (d == 2) { prr[2] = *pp2; pp2 += 256; }
                else             { prr[3] = *pp3; pp3 += 256; }
            }

            // G = h @ W_hh^T (chained MFMA pair, r9 form)
            const floatx4 z = {0.f, 0.f, 0.f, 0.f};
            floatx4 ci = mfma16(A1, Bf[0][1], mfma16(A0, Bf[0][0], z));
            floatx4 cf = mfma16(A1, Bf[1][1], mfma16(A0, Bf[1][0], z));
            floatx4 cg = mfma16(A1, Bf[2][1], mfma16(A0, Bf[2][0], z));
            floatx4 co = mfma16(A1, Bf[3][1], mfma16(A0, Bf[3][0], z));

            if (actC) {
                const float gi = bflo(pc.x) + ci[0];    // log2e-scaled
                const float gf = bfhi(pc.x) + cf[0];
                const float gg = bflo(pc.y) + cg[0];
                const float go = bfhi(pc.y) + co[0];
                c = fmaf(sigm_s(gf), c, sigm_s(gi) * tanh_s(gg));
                h = sigm_s(go) * tanh_s(c * LOG2E);
                *reinterpret_cast<unsigned short*>(lw + 128 * (cur ^ 1) + 2 * u) = cvt_bf16(h);
            }
            bar_lgkm();                  // LDS visibility only; ring stays in flight
        }
    }

    if (actC) h_out[(size_t)chain * HH + u] = h;
}

// ---------------------------------------------------------------------------
// Fallback: fully fused scan (round-1 kernel) if ws is too small for PRE.
// ---------------------------------------------------------------------------
__global__ __launch_bounds__(256, 1)
void lstm_scan_fused_kernel(const float* __restrict__ x,
                            const float* __restrict__ w_ih_f, const float* __restrict__ w_hh_f,
                            const float* __restrict__ b_ih_f, const float* __restrict__ b_hh_f,
                            const float* __restrict__ w_ih_b, const float* __restrict__ w_hh_b,
                            const float* __restrict__ b_ih_b, const float* __restrict__ b_hh_b,
                            float* __restrict__ h_out)
{
    const int blk = blockIdx.x;
    const int dir = blk >> 7;
    const int bat = blk & 127;
    const int tid = threadIdx.x;
    const int wv  = tid >> 6;
    const int ln  = tid & 63;

    const float* __restrict__ w_ih = dir ? w_ih_b : w_ih_f;
    const float* __restrict__ w_hh = dir ? w_hh_b : w_hh_f;
    const float* __restrict__ b_ih = dir ? b_ih_b : b_ih_f;
    const float* __restrict__ b_hh = dir ? b_hh_b : b_hh_f;

    float wi[FF], wh[HH];
    #pragma unroll
    for (int f = 0; f < FF; ++f) wi[f] = w_ih[tid * FF + f];
    #pragma unroll
    for (int j = 0; j < HH; ++j) wh[j] = w_hh[tid * HH + j];
    const float bias = b_ih[tid] + b_hh[tid];

    __shared__ float xs[2][FF];
    __shared__ float hbuf[4][HH];
    __shared__ float gbuf[2][256];

    const float* __restrict__ xrow = x + (size_t)bat * (TT * FF);
    float c = 0.0f, hreg = 0.0f;
    hbuf[wv][ln] = 0.0f;

    float xA = 0.0f;
    if (tid < FF) {
        xs[0][tid] = xrow[(size_t)(dir ? (TT - 1) : 0) * FF + tid];
        xA         = xrow[(size_t)(dir ? (TT - 2) : 1) * FF + tid];
    }
    __syncthreads();

    #pragma unroll 1
    for (int t = 0; t < TT; ++t) {
        const int cur = t & 1, nxt = cur ^ 1;
        float a0 = 0.f, a1 = 0.f, a2 = 0.f, a3 = 0.f;
        const float4* xs4 = reinterpret_cast<const float4*>(xs[cur]);
        #pragma unroll
        for (int f = 0; f < FF / 4; ++f) {
            float4 v = xs4[f];
            a0 = fmaf(wi[4*f+0], v.x, a0);
            a1 = fmaf(wi[4*f+1], v.y, a1);
            a2 = fmaf(wi[4*f+2], v.z, a2);
            a3 = fmaf(wi[4*f+3], v.w, a3);
        }
        const float4* hb4 = reinterpret_cast<const float4*>(hbuf[wv]);
        #pragma unroll
        for (int j = 0; j < HH / 4; ++j) {
            float4 v = hb4[j];
            a0 = fmaf(wh[4*j+0], v.x, a0);
            a1 = fmaf(wh[4*j+1], v.y, a1);
            a2 = fmaf(wh[4*j+2], v.z, a2);
            a3 = fmaf(wh[4*j+3], v.w, a3);
        }
        gbuf[cur][tid] = ((a0 + a1) + (a2 + a3)) + bias;

        if (tid < FF) {
            if (t + 1 < TT) xs[nxt][tid] = xA;
            if (t + 2 < TT) xA = xrow[(size_t)(dir ? (TT - 3 - t) : (t + 2)) * FF + tid];
        }
        __syncthreads();

        const float gi = gbuf[cur][ln];
        const float gf = gbuf[cur][64 + ln];
        const float gg = gbuf[cur][128 + ln];
        const float go = gbuf[cur][192 + ln];
        c    = sigm(gf) * c + sigm(gi) * tanh_f(gg);
        hreg = sigm(go) * tanh_f(c);
        hbuf[wv][ln] = hreg;
    }

    if (tid < HH) h_out[(size_t)(dir * 128 + bat) * HH + tid] = hreg;
}

__global__ __launch_bounds__(64, 1)
void fc_kernel(const float* __restrict__ h_out,   // [2][NB][HH]
               const float* __restrict__ w_fc,    // [8][128]
               const float* __restrict__ b_fc,    // [8]
               float* __restrict__ out)           // [NB][8]
{
    const int b = blockIdx.x;
    const int o = threadIdx.x;
    if (o < 8) {
        float acc = b_fc[o];
        #pragma unroll 4
        for (int j = 0; j < HH; ++j)
            acc = fmaf(h_out[(size_t)b * HH + j], w_fc[o * 128 + j], acc);
        #pragma unroll 4
        for (int j = 0; j < HH; ++j)
            acc = fmaf(h_out[(size_t)(NB + b) * HH + j], w_fc[o * 128 + 64 + j], acc);
        out[b * 8 + o] = acc;
    }
}

extern "C" void kernel_launch(void* const* d_in, const int* in_sizes, int n_in,
                              void* d_out, int out_size, void* d_ws, size_t ws_size,
                              hipStream_t stream) {
    const float* x      = (const float*)d_in[0];
    const float* w_ih_f = (const float*)d_in[2];
    const float* w_hh_f = (const float*)d_in[3];
    const float* b_ih_f = (const float*)d_in[4];
    const float* b_hh_f = (const float*)d_in[5];
    const float* w_ih_b = (const float*)d_in[6];
    const float* w_hh_b = (const float*)d_in[7];
    const float* b_ih_b = (const float*)d_in[8];
    const float* b_hh_b = (const float*)d_in[9];
    const float* w_fc   = (const float*)d_in[10];
    const float* b_fc   = (const float*)d_in[11];
    float* out = (float*)d_out;

    const size_t pre_bytes = (size_t)2 * NB * TT * 256 * 2;   // 512 MiB bf16
    const size_t need      = pre_bytes + 64 * 1024;

    if (ws_size >= need) {
        unsigned short* pre = (unsigned short*)d_ws;
        float* h_out = (float*)((char*)d_ws + pre_bytes);
        lstm_proj_mfma<<<dim3(256), dim3(256), 0, stream>>>(
            x, w_ih_f, b_ih_f, b_hh_f, w_ih_b, b_ih_b, b_hh_b, pre);
        lstm_scan_mfma5<<<dim3(256), dim3(256), 0, stream>>>(
            pre, w_hh_f, w_hh_b, h_out);
        fc_kernel<<<dim3(128), dim3(64), 0, stream>>>(h_out, w_fc, b_fc, out);
    } else {
        float* h_out = (float*)d_ws;   // 64 KiB
        lstm_scan_fused_kernel<<<dim3(256), dim3(256), 0, stream>>>(
            x, w_ih_f, w_hh_f, b_ih_f, b_hh_f,
            w_ih_b, w_hh_b, b_ih_b, b_hh_b, h_out);
        fc_kernel<<<dim3(128), dim3(64), 0, stream>>>(h_out, w_fc, b_fc, out);
    }
}